// Round 1
// baseline (1697.052 us; speedup 1.0000x reference)
//
#include <hip/hip_runtime.h>
#include <math.h>
#include <float.h>

#define K_CODES 8192
#define C_DIM   256
#define N_TOK   16384
#define B_      16
#define H_      32
#define W_      32
#define HW      1024   // H_*W_

// ---------------------------------------------------------------------------
// Kernel 1: normalize codebook rows; also emit s2[k] = sum(e_n[k]^2)
// (reference d includes the ||e_n||^2 term, which varies ~1e-7 across rows)
// ---------------------------------------------------------------------------
__global__ void norm_codebook(const float* __restrict__ emb,
                              float* __restrict__ e_n,
                              float* __restrict__ s2) {
    __shared__ float red[256];
    int k = blockIdx.x;
    int t = threadIdx.x;
    float v = emb[k * C_DIM + t];
    red[t] = v * v;
    __syncthreads();
    for (int s = 128; s > 0; s >>= 1) {
        if (t < s) red[t] += red[t + s];
        __syncthreads();
    }
    float inv = 1.0f / fmaxf(sqrtf(red[0]), 1e-12f);
    __syncthreads();  // everyone read red[0] before reuse
    float vn = v * inv;
    e_n[k * C_DIM + t] = vn;
    red[t] = vn * vn;
    __syncthreads();
    for (int s = 128; s > 0; s >>= 1) {
        if (t < s) red[t] += red[t + s];
        __syncthreads();
    }
    if (t == 0) s2[k] = red[0];
}

// ---------------------------------------------------------------------------
// Kernel 2: z[B,C,H,W] -> ztn[N,C] = l2-normalized tokens (transpose via LDS)
// One block per (b,h): 32 tokens x 256 channels.
// ---------------------------------------------------------------------------
__global__ void transpose_norm_z(const float* __restrict__ z,
                                 float* __restrict__ ztn) {
    __shared__ float tile[32 * 257];
    __shared__ float pvt[8 * 32];
    __shared__ float inv[32];
    int bid = blockIdx.x;          // b*32 + h
    int b = bid >> 5, h = bid & 31;
    int t = threadIdx.x;
    int w = t & 31, c0 = t >> 5;   // 8 c-groups
    const float* zb = z + ((size_t)(b * C_DIM) * H_ + h) * W_;  // +c*HW +w
    #pragma unroll
    for (int it = 0; it < 32; ++it) {
        int c = it * 8 + c0;
        tile[w * 257 + c] = zb[(size_t)c * HW + w];   // coalesced over w
    }
    __syncthreads();
    // partial sums of squares: part = t>>5, token w2 = t&31
    int part = t >> 5, w2 = t & 31;
    float s = 0.f;
    #pragma unroll
    for (int i = 0; i < 32; ++i) {
        float v = tile[w2 * 257 + part * 32 + i];
        s += v * v;
    }
    pvt[part * 32 + w2] = s;
    __syncthreads();
    if (t < 32) {
        float ss = 0.f;
        #pragma unroll
        for (int p = 0; p < 8; ++p) ss += pvt[p * 32 + t];
        inv[t] = 1.0f / fmaxf(sqrtf(ss), 1e-12f);
    }
    __syncthreads();
    int n_base = b * HW + h * W_;
    for (int r = 0; r < 32; ++r) {
        float val = tile[r * 257 + t] * inv[r];
        ztn[(size_t)(n_base + r) * C_DIM + t] = val;   // coalesced over c
    }
}

// ---------------------------------------------------------------------------
// Kernel 3: the hot loop. For each token, argmin_k ( s2[k] - 2*dot(ztn_n, e_n_k) ).
// 64 tokens x 64 codes per block, 4x4 micro-tile per thread, C chunked by 64.
// fp32 fma accuracy (bf16 MFMA would flip argmin indices).
// ---------------------------------------------------------------------------
#define TN  64
#define TK  64
#define CCH 64

__global__ __launch_bounds__(256) void score_argmin(
        const float* __restrict__ ztn, const float* __restrict__ e_n,
        const float* __restrict__ s2, int* __restrict__ idx_out,
        float* __restrict__ idxf_out) {
    __shared__ float A[CCH][TN];     // [c][token]
    __shared__ float Bm[CCH][TK];    // [c][code]
    __shared__ float s2l[TK];
    __shared__ float rv[TN][17];
    __shared__ int   ri[TN][17];
    int t = threadIdx.x;
    int tx = t & 15, ty = t >> 4;    // tx -> code dim, ty -> token dim
    int tokBase = blockIdx.x * TN;

    float best[4];
    int   bidx[4];
    #pragma unroll
    for (int j = 0; j < 4; ++j) { best[j] = FLT_MAX; bidx[j] = 0; }

    int rowLd = t & 63;              // staging: row within tile
    int cLd   = (t >> 6) * 16;       // staging: 16-channel chunk

    for (int kt = 0; kt < K_CODES; kt += TK) {
        float acc[4][4];
        #pragma unroll
        for (int j = 0; j < 4; ++j)
            #pragma unroll
            for (int i = 0; i < 4; ++i) acc[j][i] = 0.f;

        for (int cb = 0; cb < C_DIM; cb += CCH) {
            __syncthreads();   // prior readers (compute / argmin s2l) done
            if (cb == 0 && t < TK) s2l[t] = s2[kt + t];
            const float* aSrc = ztn + (size_t)(tokBase + rowLd) * C_DIM + cb + cLd;
            const float* bSrc = e_n + (size_t)(kt + rowLd) * C_DIM + cb + cLd;
            #pragma unroll
            for (int u = 0; u < 16; u += 4) {
                float4 va = *(const float4*)(aSrc + u);
                A[cLd + u + 0][rowLd] = va.x;
                A[cLd + u + 1][rowLd] = va.y;
                A[cLd + u + 2][rowLd] = va.z;
                A[cLd + u + 3][rowLd] = va.w;
                float4 vb = *(const float4*)(bSrc + u);
                Bm[cLd + u + 0][rowLd] = vb.x;
                Bm[cLd + u + 1][rowLd] = vb.y;
                Bm[cLd + u + 2][rowLd] = vb.z;
                Bm[cLd + u + 3][rowLd] = vb.w;
            }
            __syncthreads();
            #pragma unroll 8
            for (int c = 0; c < CCH; ++c) {
                float4 a = *(const float4*)&A[c][ty * 4];
                float4 b = *(const float4*)&Bm[c][tx * 4];
                acc[0][0] = fmaf(a.x, b.x, acc[0][0]);
                acc[0][1] = fmaf(a.x, b.y, acc[0][1]);
                acc[0][2] = fmaf(a.x, b.z, acc[0][2]);
                acc[0][3] = fmaf(a.x, b.w, acc[0][3]);
                acc[1][0] = fmaf(a.y, b.x, acc[1][0]);
                acc[1][1] = fmaf(a.y, b.y, acc[1][1]);
                acc[1][2] = fmaf(a.y, b.z, acc[1][2]);
                acc[1][3] = fmaf(a.y, b.w, acc[1][3]);
                acc[2][0] = fmaf(a.z, b.x, acc[2][0]);
                acc[2][1] = fmaf(a.z, b.y, acc[2][1]);
                acc[2][2] = fmaf(a.z, b.z, acc[2][2]);
                acc[2][3] = fmaf(a.z, b.w, acc[2][3]);
                acc[3][0] = fmaf(a.w, b.x, acc[3][0]);
                acc[3][1] = fmaf(a.w, b.y, acc[3][1]);
                acc[3][2] = fmaf(a.w, b.z, acc[3][2]);
                acc[3][3] = fmaf(a.w, b.w, acc[3][3]);
            }
        }
        // running argmin, jnp.argmin tie semantics (first/lowest index wins):
        // ascending i within tile, strict < across tiles (earlier kt = lower idx)
        #pragma unroll
        for (int i = 0; i < 4; ++i) {
            float s2v = s2l[tx * 4 + i];
            int kidx = kt + tx * 4 + i;
            #pragma unroll
            for (int j = 0; j < 4; ++j) {
                float sc = fmaf(-2.f, acc[j][i], s2v);
                if (sc < best[j]) { best[j] = sc; bidx[j] = kidx; }
            }
        }
    }
    __syncthreads();
    #pragma unroll
    for (int j = 0; j < 4; ++j) {
        rv[ty * 4 + j][tx] = best[j];
        ri[ty * 4 + j][tx] = bidx[j];
    }
    __syncthreads();
    if (t < TN) {
        float bv = rv[t][0];
        int   bi = ri[t][0];
        #pragma unroll
        for (int x = 1; x < 16; ++x) {
            float v = rv[t][x];
            int  i2 = ri[t][x];
            if (v < bv || (v == bv && i2 < bi)) { bv = v; bi = i2; }
        }
        int n = tokBase + t;
        idx_out[n]  = bi;
        idxf_out[n] = (float)bi;   // indices region of d_out, float32 values
    }
}

// ---------------------------------------------------------------------------
// Kernel 4: out[b,c,h,w] = e_n[idx[n], c]   (n = b*1024 + h*32 + w)
// LDS transpose tile so code-row reads and channel-strided writes both coalesce.
// ---------------------------------------------------------------------------
__global__ void gather_out(const float* __restrict__ e_n,
                           const int* __restrict__ idx,
                           float* __restrict__ out) {
    __shared__ float tile[32 * 257];
    int bid = blockIdx.x;          // b*32 + h
    int b = bid >> 5, h = bid & 31;
    int t = threadIdx.x;
    int n_base = b * HW + h * W_;
    for (int r = 0; r < 32; ++r) {
        int k = idx[n_base + r];                  // wave-uniform
        tile[r * 257 + t] = e_n[(size_t)k * C_DIM + t];   // coalesced
    }
    __syncthreads();
    int w = t & 31, c0 = t >> 5;
    float* ob = out + ((size_t)(b * C_DIM) * H_ + h) * W_;
    #pragma unroll
    for (int it = 0; it < 32; ++it) {
        int c = it * 8 + c0;
        ob[(size_t)c * HW + w] = tile[w * 257 + c];   // coalesced over w
    }
}

// ---------------------------------------------------------------------------
extern "C" void kernel_launch(void* const* d_in, const int* in_sizes, int n_in,
                              void* d_out, int out_size, void* d_ws, size_t ws_size,
                              hipStream_t stream) {
    const float* z   = (const float*)d_in[0];      // [16,256,32,32]
    const float* emb = (const float*)d_in[1];      // [8192,256]
    float* out  = (float*)d_out;                   // 4194304 floats
    float* idxf = out + (size_t)B_ * C_DIM * H_ * W_;  // 16384 floats (indices)

    float* e_n = (float*)d_ws;                         // 8192*256
    float* s2  = e_n + (size_t)K_CODES * C_DIM;        // 8192
    float* ztn = s2 + K_CODES;                         // 16384*256
    int*   idx = (int*)(ztn + (size_t)N_TOK * C_DIM);  // 16384

    hipLaunchKernelGGL(norm_codebook, dim3(K_CODES), dim3(256), 0, stream,
                       emb, e_n, s2);
    hipLaunchKernelGGL(transpose_norm_z, dim3(B_ * H_), dim3(256), 0, stream,
                       z, ztn);
    hipLaunchKernelGGL(score_argmin, dim3(N_TOK / TN), dim3(256), 0, stream,
                       ztn, e_n, s2, idx, idxf);
    hipLaunchKernelGGL(gather_out, dim3(B_ * H_), dim3(256), 0, stream,
                       e_n, idx, out);
}

// Round 2
// 385.422 us; speedup vs baseline: 4.4031x; 4.4031x over previous
//
#include <hip/hip_runtime.h>
#include <math.h>
#include <float.h>

#define K_CODES 8192
#define C_DIM   256
#define N_TOK   16384
#define B_      16
#define H_      32
#define W_      32
#define HW      1024
#define KSPLIT  4
#define TOKS_PER_BLK   128
#define CODES_PER_ITER 128

typedef short  short8  __attribute__((ext_vector_type(8)));
typedef float  floatx4 __attribute__((ext_vector_type(4)));

__device__ inline ushort f32_to_bf16_rne(float x) {
    union { float f; unsigned u; } v; v.f = x;
    unsigned u = v.u;
    return (ushort)((u + 0x7FFFu + ((u >> 16) & 1u)) >> 16);
}
__device__ inline float bf16_bits_to_f32(ushort h) {
    union { unsigned u; float f; } v; v.u = ((unsigned)h) << 16;
    return v.f;
}

// ---------------------------------------------------------------------------
// Kernel 1: normalize codebook rows -> e_n fp32, s2[k]=sum(e_n^2), bf16 hi/lo
// ---------------------------------------------------------------------------
__global__ void norm_codebook(const float* __restrict__ emb,
                              float* __restrict__ e_n,
                              float* __restrict__ s2,
                              ushort* __restrict__ Bhi,
                              ushort* __restrict__ Blo) {
    __shared__ float red[256];
    int k = blockIdx.x;
    int t = threadIdx.x;
    float v = emb[k * C_DIM + t];
    red[t] = v * v;
    __syncthreads();
    for (int s = 128; s > 0; s >>= 1) {
        if (t < s) red[t] += red[t + s];
        __syncthreads();
    }
    float inv = 1.0f / fmaxf(sqrtf(red[0]), 1e-12f);
    __syncthreads();
    float vn = v * inv;
    e_n[k * C_DIM + t] = vn;
    ushort hb = f32_to_bf16_rne(vn);
    float  hf = bf16_bits_to_f32(hb);
    Bhi[k * C_DIM + t] = hb;
    Blo[k * C_DIM + t] = f32_to_bf16_rne(vn - hf);
    red[t] = vn * vn;
    __syncthreads();
    for (int s = 128; s > 0; s >>= 1) {
        if (t < s) red[t] += red[t + s];
        __syncthreads();
    }
    if (t == 0) s2[k] = red[0];
}

// ---------------------------------------------------------------------------
// Kernel 2: z[B,C,H,W] -> ztn[N,C] fp32 normalized tokens + bf16 hi/lo
// ---------------------------------------------------------------------------
__global__ void transpose_norm_z(const float* __restrict__ z,
                                 float* __restrict__ ztn,
                                 ushort* __restrict__ Ahi,
                                 ushort* __restrict__ Alo) {
    __shared__ float tile[32 * 257];
    __shared__ float pvt[8 * 32];
    __shared__ float inv[32];
    int bid = blockIdx.x;          // b*32 + h
    int b = bid >> 5, h = bid & 31;
    int t = threadIdx.x;
    int w = t & 31, c0 = t >> 5;
    const float* zb = z + ((size_t)(b * C_DIM) * H_ + h) * W_;
    #pragma unroll
    for (int it = 0; it < 32; ++it) {
        int c = it * 8 + c0;
        tile[w * 257 + c] = zb[(size_t)c * HW + w];
    }
    __syncthreads();
    int part = t >> 5, w2 = t & 31;
    float s = 0.f;
    #pragma unroll
    for (int i = 0; i < 32; ++i) {
        float v = tile[w2 * 257 + part * 32 + i];
        s += v * v;
    }
    pvt[part * 32 + w2] = s;
    __syncthreads();
    if (t < 32) {
        float ss = 0.f;
        #pragma unroll
        for (int p = 0; p < 8; ++p) ss += pvt[p * 32 + t];
        inv[t] = 1.0f / fmaxf(sqrtf(ss), 1e-12f);
    }
    __syncthreads();
    int n_base = b * HW + h * W_;
    for (int r = 0; r < 32; ++r) {
        float val = tile[r * 257 + t] * inv[r];
        size_t off = (size_t)(n_base + r) * C_DIM + t;
        ztn[off] = val;
        ushort hb = f32_to_bf16_rne(val);
        float  hf = bf16_bits_to_f32(hb);
        Ahi[off] = hb;
        Alo[off] = f32_to_bf16_rne(val - hf);
    }
}

// ---------------------------------------------------------------------------
// Kernel 3: MFMA approximate scan. dot3 = Ahi*Bhi + Ahi*Blo + Alo*Bhi via
// chained mfma_f32_16x16x32_bf16 (error ~1e-6 on dot; score gap scale ~1e-2).
// Block: 256 thr / 4 waves; tile 128 tokens x 128 codes per K-iter.
// Each wave: 32 tokens (2 row-tiles) x 128 codes (8 col-tiles).
// Tracks per-token top-2 LARGEST dot (score = s2 - 2*dot, s2 = 1 +- 1e-7,
// so argmin score == argmax dot to below our error floor).
// Writes top-2 candidate indices per token per K-partition.
// LDS rows padded to 40 ushorts (80 B) -> 2-way (free) bank aliasing.
// ---------------------------------------------------------------------------
__global__ __launch_bounds__(256, 2) void score_topk(
        const ushort* __restrict__ Ahi, const ushort* __restrict__ Alo,
        const ushort* __restrict__ Bhi, const ushort* __restrict__ Blo,
        int* __restrict__ cand) {
    __shared__ __align__(16) char smem[40960];
    ushort (*sAhi)[40] = (ushort(*)[40])(smem);
    ushort (*sAlo)[40] = (ushort(*)[40])(smem + 10240);
    ushort (*sBhi)[40] = (ushort(*)[40])(smem + 20480);
    ushort (*sBlo)[40] = (ushort(*)[40])(smem + 30720);

    int t = threadIdx.x;
    int l = t & 63, w = t >> 6;
    int q = l >> 4, li = l & 15;
    int tokBase = blockIdx.x * TOKS_PER_BLK;
    int kpartBase = blockIdx.y * (K_CODES / KSPLIT);

    float bv1[8], bv2[8]; int bi1[8], bi2[8];
    #pragma unroll
    for (int i = 0; i < 8; ++i) { bv1[i] = -1e30f; bv2[i] = -1e30f; bi1[i] = 0; bi2[i] = 0; }

    int ldRow = t >> 2;          // 0..63
    int ldCh  = (t & 3) * 8;     // 0,8,16,24

    for (int kt = 0; kt < (K_CODES / KSPLIT) / CODES_PER_ITER; ++kt) {
        int kbase = kpartBase + kt * CODES_PER_ITER;
        floatx4 acc[2][8];
        #pragma unroll
        for (int tt = 0; tt < 2; ++tt)
            #pragma unroll
            for (int ct = 0; ct < 8; ++ct) {
                floatx4 zz = {0.f, 0.f, 0.f, 0.f};
                acc[tt][ct] = zz;
            }

        for (int cb8 = 0; cb8 < 8; ++cb8) {
            int cb = cb8 * 32;
            __syncthreads();   // previous chunk's readers done
            #pragma unroll
            for (int i = 0; i < 2; ++i) {
                int row = i * 64 + ldRow;
                size_t aoff = (size_t)(tokBase + row) * C_DIM + cb + ldCh;
                size_t boff = (size_t)(kbase + row) * C_DIM + cb + ldCh;
                uint4 vah = *(const uint4*)(Ahi + aoff);
                uint4 val_ = *(const uint4*)(Alo + aoff);
                uint4 vbh = *(const uint4*)(Bhi + boff);
                uint4 vbl = *(const uint4*)(Blo + boff);
                *(uint4*)&sAhi[row][ldCh] = vah;
                *(uint4*)&sAlo[row][ldCh] = val_;
                *(uint4*)&sBhi[row][ldCh] = vbh;
                *(uint4*)&sBlo[row][ldCh] = vbl;
            }
            __syncthreads();
            short8 ah[2], al[2];
            #pragma unroll
            for (int tt = 0; tt < 2; ++tt) {
                int ar = w * 32 + tt * 16 + li;
                ah[tt] = *(const short8*)&sAhi[ar][q * 8];
                al[tt] = *(const short8*)&sAlo[ar][q * 8];
            }
            #pragma unroll
            for (int ct = 0; ct < 8; ++ct) {
                int br = ct * 16 + li;
                short8 bh = *(const short8*)&sBhi[br][q * 8];
                short8 bl = *(const short8*)&sBlo[br][q * 8];
                #pragma unroll
                for (int tt = 0; tt < 2; ++tt) {
                    acc[tt][ct] = __builtin_amdgcn_mfma_f32_16x16x32_bf16(al[tt], bh, acc[tt][ct], 0, 0, 0);
                    acc[tt][ct] = __builtin_amdgcn_mfma_f32_16x16x32_bf16(ah[tt], bl, acc[tt][ct], 0, 0, 0);
                    acc[tt][ct] = __builtin_amdgcn_mfma_f32_16x16x32_bf16(ah[tt], bh, acc[tt][ct], 0, 0, 0);
                }
            }
        }
        // top-2 (largest dot) update; codes ascend so strict > keeps lowest idx
        #pragma unroll
        for (int tt = 0; tt < 2; ++tt) {
            #pragma unroll
            for (int ct = 0; ct < 8; ++ct) {
                int code = kbase + ct * 16 + li;
                #pragma unroll
                for (int r = 0; r < 4; ++r) {
                    float v = acc[tt][ct][r];
                    int s = tt * 4 + r;
                    if (v > bv1[s]) { bv2[s] = bv1[s]; bi2[s] = bi1[s]; bv1[s] = v; bi1[s] = code; }
                    else if (v > bv2[s]) { bv2[s] = v; bi2[s] = code; }
                }
            }
        }
    }
    // cross-lane merge: token row (l>>4)*4+r across the 16 lanes li=0..15
    __syncthreads();
    float* mv1 = (float*)(smem);
    int*   mi1 = (int*)  (smem + 8192);
    float* mv2 = (float*)(smem + 16384);
    int*   mi2 = (int*)  (smem + 24576);
    #pragma unroll
    for (int s = 0; s < 8; ++s) {
        int tt = s >> 2, r = s & 3;
        int T = w * 32 + tt * 16 + q * 4 + r;
        mv1[T * 16 + li] = bv1[s]; mi1[T * 16 + li] = bi1[s];
        mv2[T * 16 + li] = bv2[s]; mi2[T * 16 + li] = bi2[s];
    }
    __syncthreads();
    if (t < TOKS_PER_BLK) {
        float b1 = -1e30f, b2 = -1e30f; int i1 = 0, i2 = 0;
        for (int x = 0; x < 16; ++x) {
            float v = mv1[t * 16 + x]; int ii = mi1[t * 16 + x];
            if (v > b1 || (v == b1 && ii < i1)) { b2 = b1; i2 = i1; b1 = v; i1 = ii; }
            else if (v > b2 || (v == b2 && ii < i2)) { b2 = v; i2 = ii; }
            v = mv2[t * 16 + x]; ii = mi2[t * 16 + x];
            if (v > b1 || (v == b1 && ii < i1)) { b2 = b1; i2 = i1; b1 = v; i1 = ii; }
            else if (v > b2 || (v == b2 && ii < i2)) { b2 = v; i2 = ii; }
        }
        int n = tokBase + t;
        cand[((size_t)blockIdx.y * N_TOK + n) * 2 + 0] = i1;
        cand[((size_t)blockIdx.y * N_TOK + n) * 2 + 1] = i2;
    }
}

// ---------------------------------------------------------------------------
// Kernel 4: exact fp32 rescore of the 8 candidates per token, full reference
// semantics (score = s2[k] - 2*dot, jnp.argmin first-min tie break).
// One wave per token; 8 lanes per candidate.
// ---------------------------------------------------------------------------
__global__ void rescore(const float* __restrict__ ztn, const float* __restrict__ e_n,
                        const float* __restrict__ s2, const int* __restrict__ cand,
                        int* __restrict__ idx_out, float* __restrict__ idxf_out) {
    int t = threadIdx.x;
    int w = t >> 6, l = t & 63;
    int n = blockIdx.x * 4 + w;
    int cg = l >> 3, p = l & 7;
    int part = cg >> 1, slot = cg & 1;
    int cidx = cand[((size_t)part * N_TOK + n) * 2 + slot];
    const float* er = e_n + (size_t)cidx * C_DIM;
    const float* zr = ztn + (size_t)n * C_DIM;
    float s = 0.f;
    #pragma unroll
    for (int j = 0; j < 8; ++j) {
        float4 e4 = *(const float4*)(er + j * 32 + p * 4);
        float4 z4 = *(const float4*)(zr + j * 32 + p * 4);
        s = fmaf(e4.x, z4.x, s); s = fmaf(e4.y, z4.y, s);
        s = fmaf(e4.z, z4.z, s); s = fmaf(e4.w, z4.w, s);
    }
    s += __shfl_xor(s, 1); s += __shfl_xor(s, 2); s += __shfl_xor(s, 4);
    float bs = s2[cidx] - 2.f * s;
    int bi = cidx;
    #pragma unroll
    for (int d = 8; d < 64; d <<= 1) {
        float os = __shfl_xor(bs, d);
        int   oi = __shfl_xor(bi, d);
        if (os < bs || (os == bs && oi < bi)) { bs = os; bi = oi; }
    }
    if (l == 0) { idx_out[n] = bi; idxf_out[n] = (float)bi; }
}

// ---------------------------------------------------------------------------
// Kernel 5: out[b,c,h,w] = e_n[idx[n], c]
// ---------------------------------------------------------------------------
__global__ void gather_out(const float* __restrict__ e_n,
                           const int* __restrict__ idx,
                           float* __restrict__ out) {
    __shared__ float tile[32 * 257];
    int bid = blockIdx.x;
    int b = bid >> 5, h = bid & 31;
    int t = threadIdx.x;
    int n_base = b * HW + h * W_;
    for (int r = 0; r < 32; ++r) {
        int k = idx[n_base + r];
        tile[r * 257 + t] = e_n[(size_t)k * C_DIM + t];
    }
    __syncthreads();
    int w = t & 31, c0 = t >> 5;
    float* ob = out + ((size_t)(b * C_DIM) * H_ + h) * W_;
    #pragma unroll
    for (int it = 0; it < 32; ++it) {
        int c = it * 8 + c0;
        ob[(size_t)c * HW + w] = tile[w * 257 + c];
    }
}

// ---------------------------------------------------------------------------
extern "C" void kernel_launch(void* const* d_in, const int* in_sizes, int n_in,
                              void* d_out, int out_size, void* d_ws, size_t ws_size,
                              hipStream_t stream) {
    const float* z   = (const float*)d_in[0];
    const float* emb = (const float*)d_in[1];
    float* out  = (float*)d_out;
    float* idxf = out + (size_t)B_ * C_DIM * H_ * W_;

    char* ws = (char*)d_ws;
    float*  e_n  = (float*)(ws);                         size_t o = (size_t)K_CODES * C_DIM * 4;       // 8 MB
    float*  s2   = (float*)(ws + o);                     o += 32768;
    float*  ztn  = (float*)(ws + o);                     o += (size_t)N_TOK * C_DIM * 4;               // 16 MB
    ushort* Ahi  = (ushort*)(ws + o);                    o += (size_t)N_TOK * C_DIM * 2;               // 8 MB
    ushort* Alo  = (ushort*)(ws + o);                    o += (size_t)N_TOK * C_DIM * 2;               // 8 MB
    ushort* Bhi  = (ushort*)(ws + o);                    o += (size_t)K_CODES * C_DIM * 2;             // 4 MB
    ushort* Blo  = (ushort*)(ws + o);                    o += (size_t)K_CODES * C_DIM * 2;             // 4 MB
    int*    cand = (int*)(ws + o);                       o += (size_t)KSPLIT * N_TOK * 2 * 4;          // 512 KB
    int*    idx  = (int*)(ws + o);

    hipLaunchKernelGGL(norm_codebook, dim3(K_CODES), dim3(256), 0, stream,
                       emb, e_n, s2, Bhi, Blo);
    hipLaunchKernelGGL(transpose_norm_z, dim3(B_ * H_), dim3(256), 0, stream,
                       z, ztn, Ahi, Alo);
    hipLaunchKernelGGL(score_topk, dim3(N_TOK / TOKS_PER_BLK, KSPLIT), dim3(256), 0, stream,
                       Ahi, Alo, Bhi, Blo, cand);
    hipLaunchKernelGGL(rescore, dim3(N_TOK / 4), dim3(256), 0, stream,
                       ztn, e_n, s2, cand, idx, idxf);
    hipLaunchKernelGGL(gather_out, dim3(B_ * H_), dim3(256), 0, stream,
                       e_n, idx, out);
}

// Round 3
// 297.053 us; speedup vs baseline: 5.7130x; 1.2975x over previous
//
#include <hip/hip_runtime.h>
#include <math.h>
#include <float.h>

#define K_CODES 8192
#define C_DIM   256
#define N_TOK   16384
#define B_      16
#define H_      32
#define W_      32
#define HW      1024
#define KSPLIT  8
#define TOKS_PER_BLK   256
#define CODES_PER_ITER 128

typedef short  short8  __attribute__((ext_vector_type(8)));
typedef float  floatx4 __attribute__((ext_vector_type(4)));

__device__ inline ushort f32_to_bf16_rne(float x) {
    union { float f; unsigned u; } v; v.f = x;
    unsigned u = v.u;
    return (ushort)((u + 0x7FFFu + ((u >> 16) & 1u)) >> 16);
}
__device__ inline float bf16_bits_to_f32(ushort h) {
    union { unsigned u; float f; } v; v.u = ((unsigned)h) << 16;
    return v.f;
}
__device__ inline unsigned umax_(unsigned a, unsigned b) { return a > b ? a : b; }
__device__ inline unsigned umin_(unsigned a, unsigned b) { return a < b ? a : b; }

// async 16B global->LDS: gptr is per-lane (base + lane*16), lptr is wave-uniform;
// HW writes LDS at lptr + lane*16.
__device__ inline void g2l16(const void* g, void* l) {
    __builtin_amdgcn_global_load_lds((const __attribute__((address_space(1))) unsigned int*)g,
                                     (__attribute__((address_space(3))) unsigned int*)l,
                                     16, 0, 0);
}

// Swizzled global layout for bf16 matrices (rows x 256 ch):
// 16B chunk index = (RG*16 + cb)*32 + h*16 + ri
//   RG = row>>4, cb = ch>>4 (16-ch group), h = (ch>>3)&1, ri = row&15.
// Byte addr = RG*8192 + cb*512 + h*256 + ri*16.
// A wave's MFMA frag group (16 rows, 32 channels s*32..s*32+32) is then the
// contiguous 1KB at RG*8192 + s*1024 + lane*16 (lane = (l>>4)=k-quad, (l&15)=row).

// ---------------------------------------------------------------------------
// Kernel 1: codebook: l2norm rows -> e_n (row-major fp32), s2[k]=sum(e_n^2),
// plus swizzled bf16 hi/lo (Chi/Clo). One block = 32 codes.
// ---------------------------------------------------------------------------
__global__ __launch_bounds__(256) void norm_codebook32(
        const float* __restrict__ emb, float* __restrict__ e_n,
        float* __restrict__ s2, ushort* __restrict__ Chi, ushort* __restrict__ Clo) {
    __shared__ float tile[32][257];
    __shared__ float pvt[32][9];
    __shared__ float pvt2[32][9];
    __shared__ float inv[32];
    int t = threadIdx.x;
    int k0 = blockIdx.x * 32;
    int r = t >> 3, cp = t & 7;
    const float* src = emb + (size_t)(k0 + r) * C_DIM + cp * 32;
    float ss = 0.f;
    #pragma unroll
    for (int j = 0; j < 8; ++j) {
        float4 v = *(const float4*)(src + j * 4);
        tile[r][cp * 32 + j * 4 + 0] = v.x;
        tile[r][cp * 32 + j * 4 + 1] = v.y;
        tile[r][cp * 32 + j * 4 + 2] = v.z;
        tile[r][cp * 32 + j * 4 + 3] = v.w;
        ss = fmaf(v.x, v.x, ss); ss = fmaf(v.y, v.y, ss);
        ss = fmaf(v.z, v.z, ss); ss = fmaf(v.w, v.w, ss);
    }
    pvt[r][cp] = ss;
    __syncthreads();
    if (t < 32) {
        float a = 0.f;
        #pragma unroll
        for (int p = 0; p < 8; ++p) a += pvt[t][p];
        inv[t] = 1.0f / fmaxf(sqrtf(a), 1e-12f);
    }
    __syncthreads();
    float iv = inv[r];
    float s2p = 0.f;
    float* dst = e_n + (size_t)(k0 + r) * C_DIM + cp * 32;
    #pragma unroll
    for (int j = 0; j < 8; ++j) {
        float a = tile[r][cp * 32 + j * 4 + 0] * iv;
        float b = tile[r][cp * 32 + j * 4 + 1] * iv;
        float c = tile[r][cp * 32 + j * 4 + 2] * iv;
        float d = tile[r][cp * 32 + j * 4 + 3] * iv;
        s2p = fmaf(a, a, s2p); s2p = fmaf(b, b, s2p);
        s2p = fmaf(c, c, s2p); s2p = fmaf(d, d, s2p);
        float4 o = {a, b, c, d};
        *(float4*)(dst + j * 4) = o;
    }
    pvt2[r][cp] = s2p;
    __syncthreads();
    if (t < 32) {
        float a = 0.f;
        #pragma unroll
        for (int p = 0; p < 8; ++p) a += pvt2[t][p];
        s2[k0 + t] = a;
    }
    // pack swizzled hi/lo
    int baseRG = blockIdx.x * 2;
    char* chiB = (char*)Chi;
    char* cloB = (char*)Clo;
    #pragma unroll
    for (int e = 0; e < 4; ++e) {
        int p = e * 256 + t;                    // local chunk 0..1023
        int row = ((p >> 9) << 4) | (p & 15);
        int ch0 = (((p >> 5) & 15) << 4) | (((p >> 4) & 1) << 3);
        float rv = inv[row];
        union { ushort u[8]; uint4 v; } hs, ls;
        #pragma unroll
        for (int i = 0; i < 8; ++i) {
            float vv = tile[row][ch0 + i] * rv;
            ushort hb = f32_to_bf16_rne(vv);
            hs.u[i] = hb;
            ls.u[i] = f32_to_bf16_rne(vv - bf16_bits_to_f32(hb));
        }
        size_t addr = (size_t)(baseRG + (p >> 9)) * 8192 + (size_t)(p & 511) * 16;
        *(uint4*)(chiB + addr) = hs.v;
        *(uint4*)(cloB + addr) = ls.v;
    }
}

// ---------------------------------------------------------------------------
// Kernel 2: z[B,C,H,W] -> ztn[N,C] fp32 normalized tokens (row-major)
// plus swizzled bf16 hi/lo (Thi/Tlo). One block = (b,h) = 32 tokens.
// ---------------------------------------------------------------------------
__global__ __launch_bounds__(256) void transpose_norm_z(
        const float* __restrict__ z, float* __restrict__ ztn,
        ushort* __restrict__ Thi, ushort* __restrict__ Tlo) {
    __shared__ float tile[32 * 257];
    __shared__ float pvt[8 * 32];
    __shared__ float inv[32];
    int bid = blockIdx.x;          // b*32 + h
    int b = bid >> 5, h = bid & 31;
    int t = threadIdx.x;
    int w = t & 31, c0 = t >> 5;
    const float* zb = z + ((size_t)(b * C_DIM) * H_ + h) * W_;
    #pragma unroll
    for (int it = 0; it < 32; ++it) {
        int c = it * 8 + c0;
        tile[w * 257 + c] = zb[(size_t)c * HW + w];
    }
    __syncthreads();
    int part = t >> 5, w2 = t & 31;
    float s = 0.f;
    #pragma unroll
    for (int i = 0; i < 32; ++i) {
        float v = tile[w2 * 257 + part * 32 + i];
        s = fmaf(v, v, s);
    }
    pvt[part * 32 + w2] = s;
    __syncthreads();
    if (t < 32) {
        float ss = 0.f;
        #pragma unroll
        for (int p = 0; p < 8; ++p) ss += pvt[p * 32 + t];
        inv[t] = 1.0f / fmaxf(sqrtf(ss), 1e-12f);
    }
    __syncthreads();
    int n_base = bid * 32;
    for (int r = 0; r < 32; ++r) {
        float val = tile[r * 257 + t] * inv[r];
        ztn[(size_t)(n_base + r) * C_DIM + t] = val;
    }
    // pack swizzled hi/lo
    int baseRG = bid * 2;
    char* thiB = (char*)Thi;
    char* tloB = (char*)Tlo;
    #pragma unroll
    for (int e = 0; e < 4; ++e) {
        int p = e * 256 + t;
        int row = ((p >> 9) << 4) | (p & 15);
        int ch0 = (((p >> 5) & 15) << 4) | (((p >> 4) & 1) << 3);
        float rv = inv[row];
        union { ushort u[8]; uint4 v; } hs, ls;
        #pragma unroll
        for (int i = 0; i < 8; ++i) {
            float vv = tile[row * 257 + ch0 + i] * rv;
            ushort hb = f32_to_bf16_rne(vv);
            hs.u[i] = hb;
            ls.u[i] = f32_to_bf16_rne(vv - bf16_bits_to_f32(hb));
        }
        size_t addr = (size_t)(baseRG + (p >> 9)) * 8192 + (size_t)(p & 511) * 16;
        *(uint4*)(thiB + addr) = hs.v;
        *(uint4*)(tloB + addr) = ls.v;
    }
}

// ---------------------------------------------------------------------------
// Kernel 3: MFMA scan. D[code][token] = dot3 via chained 16x16x32 bf16 MFMAs
// (A-operand = codes, B-operand = tokens). Per lane: 4 token slots x 32 codes.
// Packed-key (value|index) argmax; top-2 candidates per token per partition.
// LDS: lane-linear fragment-major, staged via global_load_lds (16B).
// ---------------------------------------------------------------------------
__global__ __launch_bounds__(256, 2) void score_topk(
        const ushort* __restrict__ Chi, const ushort* __restrict__ Clo,
        const ushort* __restrict__ Thi, const ushort* __restrict__ Tlo,
        int* __restrict__ cand) {
    // LDS: A(codes): hi 8KB @0, lo 8KB @8192; B(tokens): hi 16KB @16384, lo 16KB @32768
    __shared__ __align__(16) char smem[49152];
    int t = threadIdx.x;
    int l = t & 63, wv = t >> 6;
    int q = l >> 4, li = l & 15;
    int tokBase = blockIdx.x * TOKS_PER_BLK;
    int part = blockIdx.y;
    int partBase = part * (K_CODES / KSPLIT);

    unsigned rv1[4], rv2[4]; int ri1[4], ri2[4];
    #pragma unroll
    for (int i = 0; i < 4; ++i) { rv1[i] = 0u; rv2[i] = 0u; ri1[i] = 0; ri2[i] = 0; }

    const char* chiB = (const char*)Chi;
    const char* cloB = (const char*)Clo;
    const char* thiB = (const char*)Thi;
    const char* tloB = (const char*)Tlo;
    int tokRG = tokBase >> 4;

    for (int kt = 0; kt < (K_CODES / KSPLIT) / CODES_PER_ITER; ++kt) {
        int kbase = partBase + kt * CODES_PER_ITER;
        int codeRG = kbase >> 4;
        floatx4 acc[8][4];
        #pragma unroll
        for (int ct = 0; ct < 8; ++ct)
            #pragma unroll
            for (int nt = 0; nt < 4; ++nt) {
                floatx4 zz = {0.f, 0.f, 0.f, 0.f};
                acc[ct][nt] = zz;
            }

        for (int s = 0; s < 8; ++s) {
            __syncthreads();   // prior stage's readers done
            #pragma unroll
            for (int gi = 0; gi < 12; ++gi) {
                int grp = wv * 12 + gi;
                const char* gbase;
                int ldsOff;
                if (grp < 16) {
                    int hilo = grp & 1, ct = grp >> 1;
                    gbase = (hilo ? cloB : chiB) + (size_t)(codeRG + ct) * 8192;
                    ldsOff = ((hilo << 3) + ct) << 10;
                } else {
                    int gb = grp - 16;
                    int hilo = gb & 1, g = gb >> 1;
                    gbase = (hilo ? tloB : thiB) + (size_t)(tokRG + g) * 8192;
                    ldsOff = 16384 + (((hilo << 4) + g) << 10);
                }
                g2l16(gbase + s * 1024 + (l << 4), smem + ldsOff);
            }
            __syncthreads();   // DMA drained (vmcnt(0) before barrier)

            short8 bh[4], bl[4];
            #pragma unroll
            for (int nt = 0; nt < 4; ++nt) {
                int g = wv * 4 + nt;
                bh[nt] = *(const short8*)(smem + 16384 + (g << 10) + (l << 4));
                bl[nt] = *(const short8*)(smem + 16384 + ((16 + g) << 10) + (l << 4));
            }
            #pragma unroll
            for (int ct = 0; ct < 8; ++ct) {
                short8 ah = *(const short8*)(smem + (ct << 10) + (l << 4));
                short8 al = *(const short8*)(smem + ((8 + ct) << 10) + (l << 4));
                #pragma unroll
                for (int nt = 0; nt < 4; ++nt) {
                    acc[ct][nt] = __builtin_amdgcn_mfma_f32_16x16x32_bf16(al, bh[nt], acc[ct][nt], 0, 0, 0);
                    acc[ct][nt] = __builtin_amdgcn_mfma_f32_16x16x32_bf16(ah, bl[nt], acc[ct][nt], 0, 0, 0);
                    acc[ct][nt] = __builtin_amdgcn_mfma_f32_16x16x32_bf16(ah, bh[nt], acc[ct][nt], 0, 0, 0);
                }
            }
        }

        // packed-key top-2 update. key = (bits(d*0.25+1.25) & ~31) | (ct<<2|reg)
        // 5 stolen mantissa bits => ~3e-5 dot quantization; exact rescore later.
        #pragma unroll
        for (int nt = 0; nt < 4; ++nt) {
            unsigned m1 = 0u, m2 = 0u;
            #pragma unroll
            for (int ct = 0; ct < 8; ++ct) {
                unsigned k0 = (__float_as_uint(fmaf(acc[ct][nt][0], 0.25f, 1.25f)) & 0xFFFFFFE0u) | (unsigned)((ct << 2) | 0);
                unsigned k1 = (__float_as_uint(fmaf(acc[ct][nt][1], 0.25f, 1.25f)) & 0xFFFFFFE0u) | (unsigned)((ct << 2) | 1);
                unsigned k2 = (__float_as_uint(fmaf(acc[ct][nt][2], 0.25f, 1.25f)) & 0xFFFFFFE0u) | (unsigned)((ct << 2) | 2);
                unsigned k3 = (__float_as_uint(fmaf(acc[ct][nt][3], 0.25f, 1.25f)) & 0xFFFFFFE0u) | (unsigned)((ct << 2) | 3);
                unsigned tm = umax_(umax_(k0, k1), umax_(k2, k3));
                m2 = umax_(m2, umin_(tm, m1));
                m1 = umax_(m1, tm);
            }
            int off1 = (int)(m1 & 31u), off2 = (int)(m2 & 31u);
            int c1 = kbase + ((off1 >> 2) << 4) + (q << 2) + (off1 & 3);
            int c2 = kbase + ((off2 >> 2) << 4) + (q << 2) + (off2 & 3);
            if (m1 > rv1[nt]) {
                if (m2 > rv1[nt]) { rv2[nt] = m2; ri2[nt] = c2; }
                else              { rv2[nt] = rv1[nt]; ri2[nt] = ri1[nt]; }
                rv1[nt] = m1; ri1[nt] = c1;
            } else if (m1 > rv2[nt]) {
                rv2[nt] = m1; ri2[nt] = c1;
            }
        }
    }

    // merge across the 4 lane-quads per token
    __syncthreads();
    unsigned* mk1 = (unsigned*)smem;
    int*      mi1 = (int*)(smem + 4096);
    unsigned* mk2 = (unsigned*)(smem + 8192);
    int*      mi2 = (int*)(smem + 12288);
    #pragma unroll
    for (int nt = 0; nt < 4; ++nt) {
        int T = wv * 64 + nt * 16 + li;
        mk1[T * 4 + q] = rv1[nt]; mi1[T * 4 + q] = ri1[nt];
        mk2[T * 4 + q] = rv2[nt]; mi2[T * 4 + q] = ri2[nt];
    }
    __syncthreads();
    {
        unsigned b1k = 0u, b2k = 0u; int b1i = 0x7FFFFFFF, b2i = 0x7FFFFFFF;
        #pragma unroll
        for (int qq = 0; qq < 4; ++qq) {
            unsigned k = mk1[t * 4 + qq]; int i = mi1[t * 4 + qq];
            if (k > b1k || (k == b1k && i < b1i)) { b2k = b1k; b2i = b1i; b1k = k; b1i = i; }
            else if (k > b2k || (k == b2k && i < b2i)) { b2k = k; b2i = i; }
            k = mk2[t * 4 + qq]; i = mi2[t * 4 + qq];
            if (k > b1k || (k == b1k && i < b1i)) { b2k = b1k; b2i = b1i; b1k = k; b1i = i; }
            else if (k > b2k || (k == b2k && i < b2i)) { b2k = k; b2i = i; }
        }
        int n = tokBase + t;
        cand[((size_t)part * N_TOK + n) * 2 + 0] = b1i;
        cand[((size_t)part * N_TOK + n) * 2 + 1] = b2i;
    }
}

// ---------------------------------------------------------------------------
// Kernel 4: exact fp32 rescore of 16 candidates/token (KSPLIT*2).
// One wave per token; 4 lanes per candidate; jnp.argmin tie semantics.
// ---------------------------------------------------------------------------
__global__ __launch_bounds__(256) void rescore(
        const float* __restrict__ ztn, const float* __restrict__ e_n,
        const float* __restrict__ s2, const int* __restrict__ cand,
        int* __restrict__ idx_out, float* __restrict__ idxf_out) {
    __shared__ float zrow[4][256];
    int t = threadIdx.x;
    int w = t >> 6, l = t & 63;
    int n = blockIdx.x * 4 + w;
    // stage token row
    {
        float4 v = *(const float4*)(ztn + (size_t)n * C_DIM + l * 4);
        *(float4*)&zrow[w][l * 4] = v;
    }
    __syncthreads();
    int cg = l >> 2, p = l & 3;
    int prt = cg >> 1, slot = cg & 1;
    int cidx = cand[((size_t)prt * N_TOK + n) * 2 + slot];
    const float* er = e_n + (size_t)cidx * C_DIM + p * 64;
    const float* zr = &zrow[w][p * 64];
    float s = 0.f;
    #pragma unroll
    for (int j = 0; j < 16; ++j) {
        float4 e4 = *(const float4*)(er + j * 4);
        float4 z4 = *(const float4*)(zr + j * 4);
        s = fmaf(e4.x, z4.x, s); s = fmaf(e4.y, z4.y, s);
        s = fmaf(e4.z, z4.z, s); s = fmaf(e4.w, z4.w, s);
    }
    s += __shfl_xor(s, 1); s += __shfl_xor(s, 2);
    float bs = s2[cidx] - 2.f * s;
    int bi = cidx;
    #pragma unroll
    for (int d = 4; d < 64; d <<= 1) {
        float os = __shfl_xor(bs, d);
        int   oi = __shfl_xor(bi, d);
        if (os < bs || (os == bs && oi < bi)) { bs = os; bi = oi; }
    }
    if (l == 0) { idx_out[n] = bi; idxf_out[n] = (float)bi; }
}

// ---------------------------------------------------------------------------
// Kernel 5: out[b,c,h,w] = e_n[idx[n], c]
// ---------------------------------------------------------------------------
__global__ __launch_bounds__(256) void gather_out(
        const float* __restrict__ e_n, const int* __restrict__ idx,
        float* __restrict__ out) {
    __shared__ float tile[32 * 257];
    int bid = blockIdx.x;
    int b = bid >> 5, h = bid & 31;
    int t = threadIdx.x;
    int n_base = b * HW + h * W_;
    for (int r = 0; r < 32; ++r) {
        int k = idx[n_base + r];
        tile[r * 257 + t] = e_n[(size_t)k * C_DIM + t];
    }
    __syncthreads();
    int w = t & 31, c0 = t >> 5;
    float* ob = out + ((size_t)(b * C_DIM) * H_ + h) * W_;
    #pragma unroll
    for (int it = 0; it < 32; ++it) {
        int c = it * 8 + c0;
        ob[(size_t)c * HW + w] = tile[w * 257 + c];
    }
}

// ---------------------------------------------------------------------------
extern "C" void kernel_launch(void* const* d_in, const int* in_sizes, int n_in,
                              void* d_out, int out_size, void* d_ws, size_t ws_size,
                              hipStream_t stream) {
    const float* z   = (const float*)d_in[0];
    const float* emb = (const float*)d_in[1];
    float* out  = (float*)d_out;
    float* idxf = out + (size_t)B_ * C_DIM * H_ * W_;

    char* ws = (char*)d_ws;
    size_t o = 0;
    float*  e_n  = (float*)(ws + o);  o += (size_t)K_CODES * C_DIM * 4;   // 8 MB
    float*  s2   = (float*)(ws + o);  o += 32768;
    float*  ztn  = (float*)(ws + o);  o += (size_t)N_TOK * C_DIM * 4;     // 16 MB
    ushort* Chi  = (ushort*)(ws + o); o += (size_t)K_CODES * C_DIM * 2;   // 4 MB
    ushort* Clo  = (ushort*)(ws + o); o += (size_t)K_CODES * C_DIM * 2;   // 4 MB
    ushort* Thi  = (ushort*)(ws + o); o += (size_t)N_TOK * C_DIM * 2;     // 8 MB
    ushort* Tlo  = (ushort*)(ws + o); o += (size_t)N_TOK * C_DIM * 2;     // 8 MB
    int*    cand = (int*)(ws + o);    o += (size_t)KSPLIT * N_TOK * 2 * 4; // 1 MB
    int*    idx  = (int*)(ws + o);    o += (size_t)N_TOK * 4;

    hipLaunchKernelGGL(norm_codebook32, dim3(K_CODES / 32), dim3(256), 0, stream,
                       emb, e_n, s2, Chi, Clo);
    hipLaunchKernelGGL(transpose_norm_z, dim3(B_ * H_), dim3(256), 0, stream,
                       z, ztn, Thi, Tlo);
    hipLaunchKernelGGL(score_topk, dim3(N_TOK / TOKS_PER_BLK, KSPLIT), dim3(256), 0, stream,
                       Chi, Clo, Thi, Tlo, cand);
    hipLaunchKernelGGL(rescore, dim3(N_TOK / 4), dim3(256), 0, stream,
                       ztn, e_n, s2, cand, idx, idxf);
    hipLaunchKernelGGL(gather_out, dim3(B_ * H_), dim3(256), 0, stream,
                       e_n, idx, out);
}